// Round 19
// baseline (172.994 us; speedup 1.0000x reference)
//
#include <hip/hip_runtime.h>

typedef float f32x4 __attribute__((ext_vector_type(4)));
typedef __bf16 bf16x8 __attribute__((ext_vector_type(8)));

static __device__ __forceinline__ unsigned short f2bf(float f) {
    unsigned int u = __builtin_bit_cast(unsigned int, f);
    u += 0x7fffu + ((u >> 16) & 1u);
    return (unsigned short)(u >> 16);
}
static __device__ __forceinline__ unsigned short bfc(float f) {
    return __builtin_bit_cast(unsigned short, (__bf16)f);
}

#define QSC 0.18033688011112042f   // log2(e)/sqrt(HD) folded into Q

typedef const __attribute__((address_space(1))) unsigned int gu32;
typedef __attribute__((address_space(3))) unsigned int lu32;
static __device__ __forceinline__ void gload_lds16(const unsigned short* g, unsigned short* l) {
    __builtin_amdgcn_global_load_lds((gu32*)g, (lu32*)l, 16, 0, 0);
}

// ---------------- weight transpose+convert: w[K][N] fp32 -> wT[N][K] bf16 ----------------
__global__ __launch_bounds__(256)
void transpose_w(const float* __restrict__ w, unsigned short* __restrict__ wT,
                 int K, int N) {
    __shared__ unsigned short Lt[64][65];
    const int k0 = blockIdx.x * 64, n0 = blockIdx.y * 64;
    const int t = threadIdx.x;
    const int r = t >> 4, c4 = (t & 15) * 4;
    #pragma unroll
    for (int i = 0; i < 4; i++) {
        int rr = r + i * 16;
        float4 v = *(const float4*)(w + (k0 + rr) * N + n0 + c4);
        Lt[rr][c4 + 0] = f2bf(v.x); Lt[rr][c4 + 1] = f2bf(v.y);
        Lt[rr][c4 + 2] = f2bf(v.z); Lt[rr][c4 + 3] = f2bf(v.w);
    }
    __syncthreads();
    const int rn = t >> 3, ks = (t & 7) * 8;
    #pragma unroll
    for (int i = 0; i < 2; i++) {
        int rr = rn + i * 32;
        unsigned short tmp[8];
        #pragma unroll
        for (int j = 0; j < 8; j++) tmp[j] = Lt[ks + j][rr];
        *(uint4*)(wT + (n0 + rr) * K + k0 + ks) = *(const uint4*)tmp;
    }
}

// ---------------- QKV GEMM (fp32-A reg-staged; 2-phase; granule swizzle; bounce epilogue) ----------------
// A read directly as fp32 (cvt pass deleted): loads issued at loop top, bf16
// pack + ds_write_b128 after MFMAs (T14 load-early/write-late). B via gload_lds.
__global__ __launch_bounds__(256)
void qkv_gemm2(const float* __restrict__ X,
               const unsigned short* __restrict__ Bt,
               const float* __restrict__ bias,
               unsigned short* __restrict__ q_ws,
               unsigned short* __restrict__ k_ws,
               unsigned short* __restrict__ vT_ws)
{
    const int K = 1024;
    __shared__ unsigned short LD[16384];   // Al[2][4096] | Bl[2][4096]; reused as 128x128 bounce
    const int tid = threadIdx.x;
    const int lane = tid & 63, w = tid >> 6;
    const int l15 = lane & 15, lhi = lane >> 4;
    const int m0 = blockIdx.x * 128, n0 = blockIdx.y * 128;
    const int wm = (w >> 1) * 64, wn = (w & 1) * 64;

    const int srow = w * 32 + (lane >> 2);
    const int sg = ((lane & 3) ^ ((lane >> 3) & 3)) * 8;
    const float*          gaf = X  + (size_t)(m0 + srow) * K + sg;
    const unsigned short* gb  = Bt + (size_t)(n0 + srow) * K + sg;
    const int lofs = w * 32 * 32;

    const int rc = (lhi ^ ((l15 >> 1) & 3)) * 8;

    #define ALp(c) (LD + (c) * 4096)
    #define BLp(c) (LD + 8192 + (c) * 4096)

    f32x4 acc[4][4] = {};

    // prologue: tile 0
    {
        float4 a0 = *(const float4*)(gaf);
        float4 a1 = *(const float4*)(gaf + 4);
        float4 a2 = *(const float4*)(gaf + 16 * K);
        float4 a3 = *(const float4*)(gaf + 16 * K + 4);
        union { unsigned short s[8]; uint4 v; } u0, u1;
        u0.s[0]=bfc(a0.x); u0.s[1]=bfc(a0.y); u0.s[2]=bfc(a0.z); u0.s[3]=bfc(a0.w);
        u0.s[4]=bfc(a1.x); u0.s[5]=bfc(a1.y); u0.s[6]=bfc(a1.z); u0.s[7]=bfc(a1.w);
        u1.s[0]=bfc(a2.x); u1.s[1]=bfc(a2.y); u1.s[2]=bfc(a2.z); u1.s[3]=bfc(a2.w);
        u1.s[4]=bfc(a3.x); u1.s[5]=bfc(a3.y); u1.s[6]=bfc(a3.z); u1.s[7]=bfc(a3.w);
        *(uint4*)(ALp(0) + lofs + lane * 8)       = u0.v;
        *(uint4*)(ALp(0) + lofs + 512 + lane * 8) = u1.v;
        gload_lds16(gb, BLp(0) + lofs);
        gload_lds16(gb + 16 * K, BLp(0) + lofs + 512);
    }
    __syncthreads();

    int cur = 0;
    for (int k0 = 0; k0 < K; k0 += 32) {
        const int nxt = cur ^ 1;
        float4 a0, a1, a2, a3;
        const bool more = (k0 + 32 < K);
        if (more) {
            a0 = *(const float4*)(gaf + k0 + 32);
            a1 = *(const float4*)(gaf + k0 + 36);
            a2 = *(const float4*)(gaf + k0 + 32 + 16 * K);
            a3 = *(const float4*)(gaf + k0 + 36 + 16 * K);
            gload_lds16(gb + k0 + 32,          BLp(nxt) + lofs);
            gload_lds16(gb + k0 + 32 + 16 * K, BLp(nxt) + lofs + 512);
        }
        bf16x8 af[4], bfr[4];
        #pragma unroll
        for (int m = 0; m < 4; m++)
            af[m] = *(const bf16x8*)(ALp(cur) + (wm + m * 16 + l15) * 32 + rc);
        #pragma unroll
        for (int n = 0; n < 4; n++)
            bfr[n] = *(const bf16x8*)(BLp(cur) + (wn + n * 16 + l15) * 32 + rc);
        __builtin_amdgcn_s_setprio(1);
        #pragma unroll
        for (int m = 0; m < 4; m++)
            #pragma unroll
            for (int n = 0; n < 4; n++)
                acc[m][n] = __builtin_amdgcn_mfma_f32_16x16x32_bf16(af[m], bfr[n], acc[m][n], 0, 0, 0);
        __builtin_amdgcn_s_setprio(0);
        if (more) {
            union { unsigned short s[8]; uint4 v; } u0, u1;
            u0.s[0]=bfc(a0.x); u0.s[1]=bfc(a0.y); u0.s[2]=bfc(a0.z); u0.s[3]=bfc(a0.w);
            u0.s[4]=bfc(a1.x); u0.s[5]=bfc(a1.y); u0.s[6]=bfc(a1.z); u0.s[7]=bfc(a1.w);
            u1.s[0]=bfc(a2.x); u1.s[1]=bfc(a2.y); u1.s[2]=bfc(a2.z); u1.s[3]=bfc(a2.w);
            u1.s[4]=bfc(a3.x); u1.s[5]=bfc(a3.y); u1.s[6]=bfc(a3.z); u1.s[7]=bfc(a3.w);
            *(uint4*)(ALp(nxt) + lofs + lane * 8)       = u0.v;
            *(uint4*)(ALp(nxt) + lofs + 512 + lane * 8) = u1.v;
        }
        __syncthreads();
        cur = nxt;
    }

    const int which = n0 >> 10;          // block-uniform: 0=Q 1=K 2=V
    if (which == 2) {
        #pragma unroll
        for (int n = 0; n < 4; n++) {
            int col = n0 + wn + n * 16 + l15;
            float bv = bias[col];
            int d = col & 1023;
            int h = d >> 6, hd = d & 63;
            #pragma unroll
            for (int m = 0; m < 4; m++) {
                int row0 = m0 + wm + m * 16 + lhi * 4;
                int b = row0 >> 11, t0 = row0 & 2047;
                ushort4 pk;
                pk.x = f2bf(acc[m][n][0] + bv);
                pk.y = f2bf(acc[m][n][1] + bv);
                pk.z = f2bf(acc[m][n][2] + bv);
                pk.w = f2bf(acc[m][n][3] + bv);
                *(ushort4*)(&vT_ws[((size_t)(b * 16 + h) * 64 + hd) * 2048 + t0]) = pk;
            }
        }
    } else {
        const float qs = (which == 0) ? QSC : 1.0f;
        unsigned short* q_or_k = (which == 0) ? q_ws : k_ws;
        __syncthreads();
        #pragma unroll
        for (int n = 0; n < 4; n++) {
            int col = wn + n * 16 + l15;
            float bv = bias[n0 + col];
            #pragma unroll
            for (int m = 0; m < 4; m++) {
                #pragma unroll
                for (int j = 0; j < 4; j++) {
                    int r = wm + m * 16 + lhi * 4 + j;
                    LD[r * 128 + col] = f2bf((acc[m][n][j] + bv) * qs);
                }
            }
        }
        __syncthreads();
        const int cbase = n0 & 1023;
        #pragma unroll
        for (int i = 0; i < 8; i++) {
            int e = i * 256 + tid;
            int r = e >> 4, c = (e & 15) * 8;
            uint4 v = *(const uint4*)(&LD[r * 128 + c]);
            int grow = m0 + r;
            int b = grow >> 11, t = grow & 2047;
            int gc = cbase + c;
            int h = gc >> 6, hd = gc & 63;
            *(uint4*)(&q_or_k[((size_t)(b * 16 + h) * 2048 + t) * 64 + hd]) = v;
        }
    }
    #undef ALp
    #undef BLp
}

// ---------------- Flash attention (causal) ----------------
// Unpaired q-blocks (r18-proven): grid 64x16, qb = 15 - y (LPT), 3 blocks/CU.
// m=2 amortization, no-max softmax, osum via MFMA ones-column.
#define LKK 72

__global__ __launch_bounds__(256, 2)
void attn_fwd(const unsigned short* __restrict__ q_ws,
              const unsigned short* __restrict__ k_ws,
              const unsigned short* __restrict__ vT_ws,
              unsigned short* __restrict__ attn_ws)
{
    __shared__ unsigned short Kb[2][64 * LKK];
    __shared__ unsigned short Vb[2][64 * LKK];
    __shared__ unsigned short Pl[4][2][16 * 64];

    const int bh = blockIdx.x;
    const int qb = 15 - blockIdx.y;
    const int b = bh >> 4, h = bh & 15;
    const int tid = threadIdx.x;
    const int lane = tid & 63, wid = tid >> 6;
    const int l15 = lane & 15, lhi = lane >> 4;
    const int tbase = bh * 2048;
    const float NINF = -__builtin_inff();

    const int r0 = tid >> 2;
    const int c0 = (tid & 3) * 16;
    const unsigned short* kg = k_ws + (size_t)(tbase + r0) * 64 + c0;
    const unsigned short* vg = vT_ws + ((size_t)bh * 64 + r0) * 2048 + c0;

    const int xr = l15 & 7;

    bf16x8 ones;
    #pragma unroll
    for (int z = 0; z < 8; z++) ones[z] = (__bf16)1.0f;

    const int qrow = qb * 128 + wid * 32;
    const int nkv = 2 * (qb + 1);

    bf16x8 qf[2][2];
    #pragma unroll
    for (int m = 0; m < 2; m++)
        #pragma unroll
        for (int ks = 0; ks < 2; ks++)
            qf[m][ks] = *(const bf16x8*)(q_ws + (size_t)(tbase + qrow + m * 16 + l15) * 64 + ks * 32 + lhi * 8);

    f32x4 o[2][4] = {};
    f32x4 osum[2] = {};

    *(uint4*)(&Kb[0][r0 * LKK + c0])     = *(const uint4*)(kg);
    *(uint4*)(&Kb[0][r0 * LKK + c0 + 8]) = *(const uint4*)(kg + 8);
    *(uint4*)(&Vb[0][r0 * LKK + c0])     = *(const uint4*)(vg);
    *(uint4*)(&Vb[0][r0 * LKK + c0 + 8]) = *(const uint4*)(vg + 8);
    __syncthreads();

    int cur = 0;
    for (int kb = 0; kb < nkv; ++kb) {
        const int k0 = kb * 64;
        const int knx = (kb + 1 < nkv ? kb + 1 : kb) * 64;
        uint4 ka0 = *(const uint4*)(kg + (size_t)knx * 64);
        uint4 ka1 = *(const uint4*)(kg + (size_t)knx * 64 + 8);
        uint4 va0 = *(const uint4*)(vg + knx);
        uint4 va1 = *(const uint4*)(vg + knx + 8);

        if (k0 <= qrow + 31) {
            f32x4 s[2][4] = {};
            __builtin_amdgcn_s_setprio(1);
            #pragma unroll
            for (int ks = 0; ks < 2; ks++) {
                bf16x8 kf[4];
                #pragma unroll
                for (int n = 0; n < 4; n++)
                    kf[n] = *(const bf16x8*)(&Kb[cur][(n * 16 + l15) * LKK + ks * 32 + lhi * 8]);
                #pragma unroll
                for (int m = 0; m < 2; m++)
                    #pragma unroll
                    for (int n = 0; n < 4; n++)
                        s[m][n] = __builtin_amdgcn_mfma_f32_16x16x32_bf16(kf[n], qf[m][ks], s[m][n], 0, 0, 0);
            }
            __builtin_amdgcn_s_setprio(0);
            if (k0 + 63 > qrow) {
                #pragma unroll
                for (int m = 0; m < 2; m++) {
                    int qg = qrow + m * 16 + l15;
                    #pragma unroll
                    for (int n = 0; n < 4; n++) {
                        int kgl = k0 + n * 16 + lhi * 4;
                        #pragma unroll
                        for (int j = 0; j < 4; j++)
                            s[m][n][j] = (kgl + j <= qg) ? s[m][n][j] : NINF;
                    }
                }
            }
            #pragma unroll
            for (int m = 0; m < 2; m++)
                #pragma unroll
                for (int n = 0; n < 4; n++)
                    #pragma unroll
                    for (int j = 0; j < 4; j++)
                        s[m][n][j] = exp2f(s[m][n][j]);
            #pragma unroll
            for (int m = 0; m < 2; m++)
                #pragma unroll
                for (int n = 0; n < 4; n++) {
                    ushort4 pk;
                    pk.x = bfc(s[m][n][0]); pk.y = bfc(s[m][n][1]);
                    pk.z = bfc(s[m][n][2]); pk.w = bfc(s[m][n][3]);
                    int chunk = (2 * n + (lhi >> 1)) ^ xr;
                    *(ushort4*)(&Pl[wid][m][l15 * 64 + chunk * 8 + (lhi & 1) * 4]) = pk;
                }
            __builtin_amdgcn_s_setprio(1);
            #pragma unroll
            for (int ks = 0; ks < 2; ks++) {
                int chunk = (4 * ks + lhi) ^ xr;
                bf16x8 vf[4];
                #pragma unroll
                for (int nd = 0; nd < 4; nd++)
                    vf[nd] = *(const bf16x8*)(&Vb[cur][(nd * 16 + l15) * LKK + ks * 32 + lhi * 8]);
                #pragma unroll
                for (int m = 0; m < 2; m++) {
                    bf16x8 pf = *(const bf16x8*)(&Pl[wid][m][l15 * 64 + chunk * 8]);
                    #pragma unroll
                    for (int nd = 0; nd < 4; nd++)
                        o[m][nd] = __builtin_amdgcn_mfma_f32_16x16x32_bf16(pf, vf[nd], o[m][nd], 0, 0, 0);
                    osum[m] = __builtin_amdgcn_mfma_f32_16x16x32_bf16(pf, ones, osum[m], 0, 0, 0);
                }
            }
            __builtin_amdgcn_s_setprio(0);
        }
        *(uint4*)(&Kb[cur ^ 1][r0 * LKK + c0])     = ka0;
        *(uint4*)(&Kb[cur ^ 1][r0 * LKK + c0 + 8]) = ka1;
        *(uint4*)(&Vb[cur ^ 1][r0 * LKK + c0])     = va0;
        *(uint4*)(&Vb[cur ^ 1][r0 * LKK + c0 + 8]) = va1;
        __syncthreads();
        cur ^= 1;
    }
    #pragma unroll
    for (int m = 0; m < 2; m++) {
        #pragma unroll
        for (int j = 0; j < 4; j++) {
            float inv = 1.0f / osum[m][j];
            int t = qrow + m * 16 + lhi * 4 + j;
            #pragma unroll
            for (int nd = 0; nd < 4; nd++) {
                int d = nd * 16 + l15;
                attn_ws[((size_t)(b * 2048 + t) * 16 + h) * 64 + d] = f2bf(o[m][nd][j] * inv);
            }
        }
    }
}

// ---------------- Output projection GEMM (2-phase + granule swizzle, r10-proven) ----------------
__global__ __launch_bounds__(256)
void proj_gemm2(const unsigned short* __restrict__ A,
                const unsigned short* __restrict__ Bt,
                const float* __restrict__ bias, float* __restrict__ out)
{
    const int K = 1024, N = 1024;
    __shared__ unsigned short Al[2][128 * 32];
    __shared__ unsigned short Bl[2][128 * 32];
    const int tid = threadIdx.x;
    const int lane = tid & 63, w = tid >> 6;
    const int l15 = lane & 15, lhi = lane >> 4;
    const int m0 = blockIdx.x * 128, n0 = blockIdx.y * 128;
    const int wm = (w >> 1) * 64, wn = (w & 1) * 64;

    const int srow = w * 32 + (lane >> 2);
    const int sg = ((lane & 3) ^ ((lane >> 3) & 3)) * 8;
    const unsigned short* ga = A + (size_t)(m0 + srow) * K + sg;
    const unsigned short* gb = Bt + (size_t)(n0 + srow) * K + sg;
    const int lofs = w * 32 * 32;

    const int rc = (lhi ^ ((l15 >> 1) & 3)) * 8;

    f32x4 acc[4][4] = {};

    gload_lds16(ga, &Al[0][lofs]);
    gload_lds16(ga + 16 * K, &Al[0][lofs + 512]);
    gload_lds16(gb, &Bl[0][lofs]);
    gload_lds16(gb + 16 * K, &Bl[0][lofs + 512]);
    __syncthreads();

    int cur = 0;
    for (int k0 = 0; k0 < K; k0 += 32) {
        const int nxt = cur ^ 1;
        if (k0 + 32 < K) {
            gload_lds16(ga + k0 + 32,          &Al[nxt][lofs]);
            gload_lds16(ga + k0 + 32 + 16 * K, &Al[nxt][lofs + 512]);
            gload_lds16(gb + k0 + 32,          &Bl[nxt][lofs]);
            gload_lds16(gb + k0 + 32 + 16 * K, &Bl[nxt][lofs + 512]);
        }
        bf16x8 af[4], bfr[4];
        #pragma unroll
        for (int m = 0; m < 4; m++)
            af[m] = *(const bf16x8*)(&Al[cur][(wm + m * 16 + l15) * 32 + rc]);
        #pragma unroll
        for (int n = 0; n < 4; n++)
            bfr[n] = *(const bf16x8*)(&Bl[cur][(wn + n * 16 + l15) * 32 + rc]);
        __builtin_amdgcn_s_setprio(1);
        #pragma unroll
        for (int m = 0; m < 4; m++)
            #pragma unroll
            for (int n = 0; n < 4; n++)
                acc[m][n] = __builtin_amdgcn_mfma_f32_16x16x32_bf16(af[m], bfr[n], acc[m][n], 0, 0, 0);
        __builtin_amdgcn_s_setprio(0);
        __syncthreads();
        cur = nxt;
    }

    #pragma unroll
    for (int n = 0; n < 4; n++) {
        int col = n0 + wn + n * 16 + l15;
        float bv = bias[col];
        #pragma unroll
        for (int m = 0; m < 4; m++)
            #pragma unroll
            for (int j = 0; j < 4; j++) {
                int row = m0 + wm + m * 16 + lhi * 4 + j;
                out[row * N + col] = acc[m][n][j] + bv;
            }
    }
}

extern "C" void kernel_launch(void* const* d_in, const int* in_sizes, int n_in,
                              void* d_out, int out_size, void* d_ws, size_t ws_size,
                              hipStream_t stream)
{
    const float* x      = (const float*)d_in[0];
    const float* w_qkv  = (const float*)d_in[1];
    const float* b_qkv  = (const float*)d_in[2];
    const float* w_proj = (const float*)d_in[3];
    const float* b_proj = (const float*)d_in[4];
    float* out = (float*)d_out;

    const size_t SEG = (size_t)8 * 1024 * 1024;
    unsigned short* q_ws    = (unsigned short*)d_ws;
    unsigned short* k_ws    = q_ws + SEG;
    unsigned short* vT_ws   = k_ws + SEG;
    unsigned short* attn_ws = vT_ws + SEG;

    unsigned short* wqkvT  = (unsigned short*)d_out;          // d_out as scratch (dead before proj)
    unsigned short* wprojT = q_ws;                            // dead after attn

    transpose_w<<<dim3(16, 48), 256, 0, stream>>>(w_qkv, wqkvT, 1024, 3072);
    qkv_gemm2<<<dim3(64, 24), 256, 0, stream>>>(x, wqkvT, b_qkv, q_ws, k_ws, vT_ws);
    attn_fwd<<<dim3(64, 16), 256, 0, stream>>>(q_ws, k_ws, vT_ws, attn_ws);
    transpose_w<<<dim3(16, 16), 256, 0, stream>>>(w_proj, wprojT, 1024, 1024);
    proj_gemm2<<<dim3(64, 8), 256, 0, stream>>>(attn_ws, wprojT, b_proj, out);
}

// Round 20
// 165.378 us; speedup vs baseline: 1.0460x; 1.0460x over previous
//
#include <hip/hip_runtime.h>

typedef float f32x4 __attribute__((ext_vector_type(4)));
typedef __bf16 bf16x8 __attribute__((ext_vector_type(8)));

static __device__ __forceinline__ unsigned short f2bf(float f) {
    unsigned int u = __builtin_bit_cast(unsigned int, f);
    u += 0x7fffu + ((u >> 16) & 1u);
    return (unsigned short)(u >> 16);
}
static __device__ __forceinline__ unsigned short bfc(float f) {
    return __builtin_bit_cast(unsigned short, (__bf16)f);
}

#define QSC 0.18033688011112042f   // log2(e)/sqrt(HD) folded into Q

typedef const __attribute__((address_space(1))) unsigned int gu32;
typedef __attribute__((address_space(3))) unsigned int lu32;
static __device__ __forceinline__ void gload_lds16(const unsigned short* g, unsigned short* l) {
    __builtin_amdgcn_global_load_lds((gu32*)g, (lu32*)l, 16, 0, 0);
}

// ---------------- fp32 -> bf16 elementwise convert ----------------
__global__ __launch_bounds__(256)
void cvt_bf16(const float* __restrict__ in, unsigned short* __restrict__ out) {
    int i = blockIdx.x * 256 + threadIdx.x;
    const float4* p = (const float4*)in + (size_t)i * 2;
    float4 a = p[0], b = p[1];
    union { unsigned short s[8]; uint4 v; } u;
    u.s[0] = f2bf(a.x); u.s[1] = f2bf(a.y); u.s[2] = f2bf(a.z); u.s[3] = f2bf(a.w);
    u.s[4] = f2bf(b.x); u.s[5] = f2bf(b.y); u.s[6] = f2bf(b.z); u.s[7] = f2bf(b.w);
    ((uint4*)out)[i] = u.v;
}

// ---------------- weight transpose+convert: w[K][N] fp32 -> wT[N][K] bf16 ----------------
__global__ __launch_bounds__(256)
void transpose_w(const float* __restrict__ w, unsigned short* __restrict__ wT,
                 int K, int N) {
    __shared__ unsigned short Lt[64][65];
    const int k0 = blockIdx.x * 64, n0 = blockIdx.y * 64;
    const int t = threadIdx.x;
    const int r = t >> 4, c4 = (t & 15) * 4;
    #pragma unroll
    for (int i = 0; i < 4; i++) {
        int rr = r + i * 16;
        float4 v = *(const float4*)(w + (k0 + rr) * N + n0 + c4);
        Lt[rr][c4 + 0] = f2bf(v.x); Lt[rr][c4 + 1] = f2bf(v.y);
        Lt[rr][c4 + 2] = f2bf(v.z); Lt[rr][c4 + 3] = f2bf(v.w);
    }
    __syncthreads();
    const int rn = t >> 3, ks = (t & 7) * 8;
    #pragma unroll
    for (int i = 0; i < 2; i++) {
        int rr = rn + i * 32;
        unsigned short tmp[8];
        #pragma unroll
        for (int j = 0; j < 8; j++) tmp[j] = Lt[ks + j][rr];
        *(uint4*)(wT + (n0 + rr) * K + k0 + ks) = *(const uint4*)tmp;
    }
}

// ---------------- QKV GEMM (2-phase prefetch + granule swizzle + LDS-bounce epilogue) ----------------
__global__ __launch_bounds__(256)
void qkv_gemm2(const unsigned short* __restrict__ A,
               const unsigned short* __restrict__ Bt,
               const float* __restrict__ bias,
               unsigned short* __restrict__ q_ws,
               unsigned short* __restrict__ k_ws,
               unsigned short* __restrict__ vT_ws)
{
    const int K = 1024;
    __shared__ unsigned short LD[16384];   // Al[2][4096] | Bl[2][4096]; reused as 128x128 bounce
    const int tid = threadIdx.x;
    const int lane = tid & 63, w = tid >> 6;
    const int l15 = lane & 15, lhi = lane >> 4;
    const int m0 = blockIdx.x * 128, n0 = blockIdx.y * 128;
    const int wm = (w >> 1) * 64, wn = (w & 1) * 64;

    const int srow = w * 32 + (lane >> 2);
    const int sg = ((lane & 3) ^ ((lane >> 3) & 3)) * 8;
    const unsigned short* ga = A + (size_t)(m0 + srow) * K + sg;
    const unsigned short* gb = Bt + (size_t)(n0 + srow) * K + sg;
    const int lofs = w * 32 * 32;

    const int rc = (lhi ^ ((l15 >> 1) & 3)) * 8;

    #define ALp(c) (LD + (c) * 4096)
    #define BLp(c) (LD + 8192 + (c) * 4096)

    f32x4 acc[4][4] = {};

    gload_lds16(ga, ALp(0) + lofs);
    gload_lds16(ga + 16 * K, ALp(0) + lofs + 512);
    gload_lds16(gb, BLp(0) + lofs);
    gload_lds16(gb + 16 * K, BLp(0) + lofs + 512);
    __syncthreads();

    int cur = 0;
    for (int k0 = 0; k0 < K; k0 += 32) {
        const int nxt = cur ^ 1;
        if (k0 + 32 < K) {
            gload_lds16(ga + k0 + 32,          ALp(nxt) + lofs);
            gload_lds16(ga + k0 + 32 + 16 * K, ALp(nxt) + lofs + 512);
            gload_lds16(gb + k0 + 32,          BLp(nxt) + lofs);
            gload_lds16(gb + k0 + 32 + 16 * K, BLp(nxt) + lofs + 512);
        }
        bf16x8 af[4], bfr[4];
        #pragma unroll
        for (int m = 0; m < 4; m++)
            af[m] = *(const bf16x8*)(ALp(cur) + (wm + m * 16 + l15) * 32 + rc);
        #pragma unroll
        for (int n = 0; n < 4; n++)
            bfr[n] = *(const bf16x8*)(BLp(cur) + (wn + n * 16 + l15) * 32 + rc);
        __builtin_amdgcn_s_setprio(1);
        #pragma unroll
        for (int m = 0; m < 4; m++)
            #pragma unroll
            for (int n = 0; n < 4; n++)
                acc[m][n] = __builtin_amdgcn_mfma_f32_16x16x32_bf16(af[m], bfr[n], acc[m][n], 0, 0, 0);
        __builtin_amdgcn_s_setprio(0);
        __syncthreads();
        cur = nxt;
    }

    const int which = n0 >> 10;          // block-uniform: 0=Q 1=K 2=V
    if (which == 2) {
        #pragma unroll
        for (int n = 0; n < 4; n++) {
            int col = n0 + wn + n * 16 + l15;
            float bv = bias[col];
            int d = col & 1023;
            int h = d >> 6, hd = d & 63;
            #pragma unroll
            for (int m = 0; m < 4; m++) {
                int row0 = m0 + wm + m * 16 + lhi * 4;
                int b = row0 >> 11, t0 = row0 & 2047;
                ushort4 pk;
                pk.x = f2bf(acc[m][n][0] + bv);
                pk.y = f2bf(acc[m][n][1] + bv);
                pk.z = f2bf(acc[m][n][2] + bv);
                pk.w = f2bf(acc[m][n][3] + bv);
                *(ushort4*)(&vT_ws[((size_t)(b * 16 + h) * 64 + hd) * 2048 + t0]) = pk;
            }
        }
    } else {
        const float qs = (which == 0) ? QSC : 1.0f;
        unsigned short* q_or_k = (which == 0) ? q_ws : k_ws;
        __syncthreads();
        #pragma unroll
        for (int n = 0; n < 4; n++) {
            int col = wn + n * 16 + l15;
            float bv = bias[n0 + col];
            #pragma unroll
            for (int m = 0; m < 4; m++) {
                #pragma unroll
                for (int j = 0; j < 4; j++) {
                    int r = wm + m * 16 + lhi * 4 + j;
                    LD[r * 128 + col] = f2bf((acc[m][n][j] + bv) * qs);
                }
            }
        }
        __syncthreads();
        const int cbase = n0 & 1023;
        #pragma unroll
        for (int i = 0; i < 8; i++) {
            int e = i * 256 + tid;
            int r = e >> 4, c = (e & 15) * 8;
            uint4 v = *(const uint4*)(&LD[r * 128 + c]);
            int grow = m0 + r;
            int b = grow >> 11, t = grow & 2047;
            int gc = cbase + c;
            int h = gc >> 6, hd = gc & 63;
            *(uint4*)(&q_or_k[((size_t)(b * 16 + h) * 2048 + t) * 64 + hd]) = v;
        }
    }
    #undef ALp
    #undef BLp
}

// ---------------- Flash attention (causal) ----------------
// Unpaired q-blocks: grid 64x16, qb = 15 - y (LPT), 3 blocks/CU.
// m=2 amortization, no-max softmax, osum via MFMA ones-column.
#define LKK 72

__global__ __launch_bounds__(256, 2)
void attn_fwd(const unsigned short* __restrict__ q_ws,
              const unsigned short* __restrict__ k_ws,
              const unsigned short* __restrict__ vT_ws,
              unsigned short* __restrict__ attn_ws)
{
    __shared__ unsigned short Kb[2][64 * LKK];
    __shared__ unsigned short Vb[2][64 * LKK];
    __shared__ unsigned short Pl[4][2][16 * 64];

    const int bh = blockIdx.x;
    const int qb = 15 - blockIdx.y;
    const int b = bh >> 4, h = bh & 15;
    const int tid = threadIdx.x;
    const int lane = tid & 63, wid = tid >> 6;
    const int l15 = lane & 15, lhi = lane >> 4;
    const int tbase = bh * 2048;
    const float NINF = -__builtin_inff();

    const int r0 = tid >> 2;
    const int c0 = (tid & 3) * 16;
    const unsigned short* kg = k_ws + (size_t)(tbase + r0) * 64 + c0;
    const unsigned short* vg = vT_ws + ((size_t)bh * 64 + r0) * 2048 + c0;

    const int xr = l15 & 7;

    bf16x8 ones;
    #pragma unroll
    for (int z = 0; z < 8; z++) ones[z] = (__bf16)1.0f;

    const int qrow = qb * 128 + wid * 32;
    const int nkv = 2 * (qb + 1);

    bf16x8 qf[2][2];
    #pragma unroll
    for (int m = 0; m < 2; m++)
        #pragma unroll
        for (int ks = 0; ks < 2; ks++)
            qf[m][ks] = *(const bf16x8*)(q_ws + (size_t)(tbase + qrow + m * 16 + l15) * 64 + ks * 32 + lhi * 8);

    f32x4 o[2][4] = {};
    f32x4 osum[2] = {};

    *(uint4*)(&Kb[0][r0 * LKK + c0])     = *(const uint4*)(kg);
    *(uint4*)(&Kb[0][r0 * LKK + c0 + 8]) = *(const uint4*)(kg + 8);
    *(uint4*)(&Vb[0][r0 * LKK + c0])     = *(const uint4*)(vg);
    *(uint4*)(&Vb[0][r0 * LKK + c0 + 8]) = *(const uint4*)(vg + 8);
    __syncthreads();

    int cur = 0;
    for (int kb = 0; kb < nkv; ++kb) {
        const int k0 = kb * 64;
        const int knx = (kb + 1 < nkv ? kb + 1 : kb) * 64;
        uint4 ka0 = *(const uint4*)(kg + (size_t)knx * 64);
        uint4 ka1 = *(const uint4*)(kg + (size_t)knx * 64 + 8);
        uint4 va0 = *(const uint4*)(vg + knx);
        uint4 va1 = *(const uint4*)(vg + knx + 8);

        if (k0 <= qrow + 31) {
            f32x4 s[2][4] = {};
            __builtin_amdgcn_s_setprio(1);
            #pragma unroll
            for (int ks = 0; ks < 2; ks++) {
                bf16x8 kf[4];
                #pragma unroll
                for (int n = 0; n < 4; n++)
                    kf[n] = *(const bf16x8*)(&Kb[cur][(n * 16 + l15) * LKK + ks * 32 + lhi * 8]);
                #pragma unroll
                for (int m = 0; m < 2; m++)
                    #pragma unroll
                    for (int n = 0; n < 4; n++)
                        s[m][n] = __builtin_amdgcn_mfma_f32_16x16x32_bf16(kf[n], qf[m][ks], s[m][n], 0, 0, 0);
            }
            __builtin_amdgcn_s_setprio(0);
            if (k0 + 63 > qrow) {
                #pragma unroll
                for (int m = 0; m < 2; m++) {
                    int qg = qrow + m * 16 + l15;
                    #pragma unroll
                    for (int n = 0; n < 4; n++) {
                        int kgl = k0 + n * 16 + lhi * 4;
                        #pragma unroll
                        for (int j = 0; j < 4; j++)
                            s[m][n][j] = (kgl + j <= qg) ? s[m][n][j] : NINF;
                    }
                }
            }
            #pragma unroll
            for (int m = 0; m < 2; m++)
                #pragma unroll
                for (int n = 0; n < 4; n++)
                    #pragma unroll
                    for (int j = 0; j < 4; j++)
                        s[m][n][j] = exp2f(s[m][n][j]);
            #pragma unroll
            for (int m = 0; m < 2; m++)
                #pragma unroll
                for (int n = 0; n < 4; n++) {
                    ushort4 pk;
                    pk.x = bfc(s[m][n][0]); pk.y = bfc(s[m][n][1]);
                    pk.z = bfc(s[m][n][2]); pk.w = bfc(s[m][n][3]);
                    int chunk = (2 * n + (lhi >> 1)) ^ xr;
                    *(ushort4*)(&Pl[wid][m][l15 * 64 + chunk * 8 + (lhi & 1) * 4]) = pk;
                }
            __builtin_amdgcn_s_setprio(1);
            #pragma unroll
            for (int ks = 0; ks < 2; ks++) {
                int chunk = (4 * ks + lhi) ^ xr;
                bf16x8 vf[4];
                #pragma unroll
                for (int nd = 0; nd < 4; nd++)
                    vf[nd] = *(const bf16x8*)(&Vb[cur][(nd * 16 + l15) * LKK + ks * 32 + lhi * 8]);
                #pragma unroll
                for (int m = 0; m < 2; m++) {
                    bf16x8 pf = *(const bf16x8*)(&Pl[wid][m][l15 * 64 + chunk * 8]);
                    #pragma unroll
                    for (int nd = 0; nd < 4; nd++)
                        o[m][nd] = __builtin_amdgcn_mfma_f32_16x16x32_bf16(pf, vf[nd], o[m][nd], 0, 0, 0);
                    osum[m] = __builtin_amdgcn_mfma_f32_16x16x32_bf16(pf, ones, osum[m], 0, 0, 0);
                }
            }
            __builtin_amdgcn_s_setprio(0);
        }
        *(uint4*)(&Kb[cur ^ 1][r0 * LKK + c0])     = ka0;
        *(uint4*)(&Kb[cur ^ 1][r0 * LKK + c0 + 8]) = ka1;
        *(uint4*)(&Vb[cur ^ 1][r0 * LKK + c0])     = va0;
        *(uint4*)(&Vb[cur ^ 1][r0 * LKK + c0 + 8]) = va1;
        __syncthreads();
        cur ^= 1;
    }
    #pragma unroll
    for (int m = 0; m < 2; m++) {
        #pragma unroll
        for (int j = 0; j < 4; j++) {
            float inv = 1.0f / osum[m][j];
            int t = qrow + m * 16 + lhi * 4 + j;
            #pragma unroll
            for (int nd = 0; nd < 4; nd++) {
                int d = nd * 16 + l15;
                attn_ws[((size_t)(b * 2048 + t) * 16 + h) * 64 + d] = f2bf(o[m][nd][j] * inv);
            }
        }
    }
}

// ---------------- Output projection GEMM (2-phase + granule swizzle, r10-proven) ----------------
__global__ __launch_bounds__(256)
void proj_gemm2(const unsigned short* __restrict__ A,
                const unsigned short* __restrict__ Bt,
                const float* __restrict__ bias, float* __restrict__ out)
{
    const int K = 1024, N = 1024;
    __shared__ unsigned short Al[2][128 * 32];
    __shared__ unsigned short Bl[2][128 * 32];
    const int tid = threadIdx.x;
    const int lane = tid & 63, w = tid >> 6;
    const int l15 = lane & 15, lhi = lane >> 4;
    const int m0 = blockIdx.x * 128, n0 = blockIdx.y * 128;
    const int wm = (w >> 1) * 64, wn = (w & 1) * 64;

    const int srow = w * 32 + (lane >> 2);
    const int sg = ((lane & 3) ^ ((lane >> 3) & 3)) * 8;
    const unsigned short* ga = A + (size_t)(m0 + srow) * K + sg;
    const unsigned short* gb = Bt + (size_t)(n0 + srow) * K + sg;
    const int lofs = w * 32 * 32;

    const int rc = (lhi ^ ((l15 >> 1) & 3)) * 8;

    f32x4 acc[4][4] = {};

    gload_lds16(ga, &Al[0][lofs]);
    gload_lds16(ga + 16 * K, &Al[0][lofs + 512]);
    gload_lds16(gb, &Bl[0][lofs]);
    gload_lds16(gb + 16 * K, &Bl[0][lofs + 512]);
    __syncthreads();

    int cur = 0;
    for (int k0 = 0; k0 < K; k0 += 32) {
        const int nxt = cur ^ 1;
        if (k0 + 32 < K) {
            gload_lds16(ga + k0 + 32,          &Al[nxt][lofs]);
            gload_lds16(ga + k0 + 32 + 16 * K, &Al[nxt][lofs + 512]);
            gload_lds16(gb + k0 + 32,          &Bl[nxt][lofs]);
            gload_lds16(gb + k0 + 32 + 16 * K, &Bl[nxt][lofs + 512]);
        }
        bf16x8 af[4], bfr[4];
        #pragma unroll
        for (int m = 0; m < 4; m++)
            af[m] = *(const bf16x8*)(&Al[cur][(wm + m * 16 + l15) * 32 + rc]);
        #pragma unroll
        for (int n = 0; n < 4; n++)
            bfr[n] = *(const bf16x8*)(&Bl[cur][(wn + n * 16 + l15) * 32 + rc]);
        __builtin_amdgcn_s_setprio(1);
        #pragma unroll
        for (int m = 0; m < 4; m++)
            #pragma unroll
            for (int n = 0; n < 4; n++)
                acc[m][n] = __builtin_amdgcn_mfma_f32_16x16x32_bf16(af[m], bfr[n], acc[m][n], 0, 0, 0);
        __builtin_amdgcn_s_setprio(0);
        __syncthreads();
        cur = nxt;
    }

    #pragma unroll
    for (int n = 0; n < 4; n++) {
        int col = n0 + wn + n * 16 + l15;
        float bv = bias[col];
        #pragma unroll
        for (int m = 0; m < 4; m++)
            #pragma unroll
            for (int j = 0; j < 4; j++) {
                int row = m0 + wm + m * 16 + lhi * 4 + j;
                out[row * N + col] = acc[m][n][j] + bv;
            }
    }
}

extern "C" void kernel_launch(void* const* d_in, const int* in_sizes, int n_in,
                              void* d_out, int out_size, void* d_ws, size_t ws_size,
                              hipStream_t stream)
{
    const float* x      = (const float*)d_in[0];
    const float* w_qkv  = (const float*)d_in[1];
    const float* b_qkv  = (const float*)d_in[2];
    const float* w_proj = (const float*)d_in[3];
    const float* b_proj = (const float*)d_in[4];
    float* out = (float*)d_out;

    const size_t SEG = (size_t)8 * 1024 * 1024;
    unsigned short* q_ws    = (unsigned short*)d_ws;
    unsigned short* k_ws    = q_ws + SEG;
    unsigned short* vT_ws   = k_ws + SEG;
    unsigned short* attn_ws = vT_ws + SEG;

    unsigned short* x_bf   = (unsigned short*)d_out;          // d_out as scratch
    unsigned short* wqkvT  = x_bf + SEG;
    unsigned short* wprojT = q_ws;                            // dead after attn

    cvt_bf16<<<4096, 256, 0, stream>>>(x, x_bf);
    transpose_w<<<dim3(16, 48), 256, 0, stream>>>(w_qkv, wqkvT, 1024, 3072);
    qkv_gemm2<<<dim3(64, 24), 256, 0, stream>>>(x_bf, wqkvT, b_qkv, q_ws, k_ws, vT_ws);
    attn_fwd<<<dim3(64, 16), 256, 0, stream>>>(q_ws, k_ws, vT_ws, attn_ws);
    transpose_w<<<dim3(16, 16), 256, 0, stream>>>(w_proj, wprojT, 1024, 1024);
    proj_gemm2<<<dim3(64, 8), 256, 0, stream>>>(attn_ws, wprojT, b_proj, out);
}